// Round 2
// baseline (226.716 us; speedup 1.0000x reference)
//
#include <hip/hip_runtime.h>

// Problem constants
#define R_PIX 123904            // 352*352
#define NVIEW 8                 // B*V
#define NPIX  (R_PIX * (size_t)NVIEW)   // 991232

// Output element offsets (flat, in fp32 elements)
#define OFF_MEANS  ((size_t)0)
#define OFF_COV    ((size_t)2973696)     // 3*NPIX
#define OFF_SCALES ((size_t)11894784)    // +9*NPIX
#define OFF_ROT    ((size_t)14868480)    // +3*NPIX
#define OFF_HARM   ((size_t)18833408)    // +4*NPIX
#define OFF_OPAC   ((size_t)30728192)    // +12*NPIX

__global__ __launch_bounds__(256) void gaussian_adapter_kernel(
    const float* __restrict__ extr,    // [8,16] (4x4 row-major)
    const float* __restrict__ intr,    // [8,9]  (3x3 row-major)
    const float* __restrict__ coords,  // [8, R, 2]
    const float* __restrict__ depths,  // [8, R]
    const float* __restrict__ opac,    // [8, R]
    const float* __restrict__ raw,     // [8, R, 19]
    const float* __restrict__ imgs,    // [8, 3, R]  (B,V,3,H,W)
    const float* __restrict__ shmask,  // [4]
    float* __restrict__ out)
{
    const int bv = blockIdx.y;
    const int p  = blockIdx.x * blockDim.x + threadIdx.x;
    const size_t pix = (size_t)bv * R_PIX + p;

    // ---- per-view constants (broadcast loads, L1-resident) ----
    float Rc[3][3], tvec[3];
    {
        const float* E = extr + bv * 16;
        #pragma unroll
        for (int i = 0; i < 3; i++) {
            #pragma unroll
            for (int j = 0; j < 3; j++) Rc[i][j] = E[i * 4 + j];
            tvec[i] = E[i * 4 + 3];
        }
    }
    const float* K = intr + bv * 9;
    const float fx = K[0], cx = K[2];
    const float fy = K[4], cy = K[5];
    float sm[4];
    #pragma unroll
    for (int j = 0; j < 4; j++) sm[j] = shmask[j];

    // ---- load raw gaussians (19 f32) ----
    float rg[19];
    {
        const float* rp = raw + pix * 19;
        #pragma unroll
        for (int i = 0; i < 19; i++) rg[i] = rp[i];
    }

    // ---- scales: clip(softplus(raw-4), 0.5, 15) ----
    float sc[3];
    #pragma unroll
    for (int k = 0; k < 3; k++) {
        float xv = rg[k] - 4.0f;
        float sp = fmaxf(xv, 0.0f) + log1pf(expf(-fabsf(xv)));   // stable softplus
        sc[k] = fminf(fmaxf(sp, 0.5f), 15.0f);
    }

    // ---- rotations: q / (||q|| + 1e-8) ----
    float q[4];
    float qn = 0.0f;
    #pragma unroll
    for (int k = 0; k < 4; k++) { q[k] = rg[3 + k]; qn += q[k] * q[k]; }
    const float inorm = 1.0f / (sqrtf(qn) + 1e-8f);
    #pragma unroll
    for (int k = 0; k < 4; k++) q[k] *= inorm;

    // ---- sh = raw[7:].reshape(3,4) * sh_mask; DC += (img-0.5)/C0 ----
    float sh[3][4];
    #pragma unroll
    for (int c = 0; c < 3; c++)
        #pragma unroll
        for (int j = 0; j < 4; j++) sh[c][j] = rg[7 + c * 4 + j] * sm[j];
    {
        const float invC0 = 1.0f / 0.28209479177387814f;
        #pragma unroll
        for (int c = 0; c < 3; c++) {
            float im = imgs[((size_t)bv * 3 + c) * R_PIX + p];
            sh[c][0] += (im - 0.5f) * invC0;
        }
    }

    // ---- quat -> rotation matrix ----
    const float qw = q[0], qx = q[1], qy = q[2], qz = q[3];
    const float two_s = 2.0f / (qw * qw + qx * qx + qy * qy + qz * qz);
    float Rq[3][3];
    Rq[0][0] = 1.0f - two_s * (qy * qy + qz * qz);
    Rq[0][1] = two_s * (qx * qy - qz * qw);
    Rq[0][2] = two_s * (qx * qz + qy * qw);
    Rq[1][0] = two_s * (qx * qy + qz * qw);
    Rq[1][1] = 1.0f - two_s * (qx * qx + qz * qz);
    Rq[1][2] = two_s * (qy * qz - qx * qw);
    Rq[2][0] = two_s * (qx * qz - qy * qw);
    Rq[2][1] = two_s * (qy * qz + qx * qw);
    Rq[2][2] = 1.0f - two_s * (qx * qx + qy * qy);

    // ---- cov3 = Rq diag(s^2) Rq^T ; cov = Rc cov3 Rc^T ----
    const float s2[3] = { sc[0] * sc[0], sc[1] * sc[1], sc[2] * sc[2] };
    float cov3[3][3];
    #pragma unroll
    for (int i = 0; i < 3; i++)
        #pragma unroll
        for (int k = 0; k < 3; k++)
            cov3[i][k] = Rq[i][0] * s2[0] * Rq[k][0]
                       + Rq[i][1] * s2[1] * Rq[k][1]
                       + Rq[i][2] * s2[2] * Rq[k][2];
    float M[3][3];
    #pragma unroll
    for (int i = 0; i < 3; i++)
        #pragma unroll
        for (int k = 0; k < 3; k++)
            M[i][k] = Rc[i][0] * cov3[0][k] + Rc[i][1] * cov3[1][k] + Rc[i][2] * cov3[2][k];
    float cov[3][3];
    #pragma unroll
    for (int i = 0; i < 3; i++)
        #pragma unroll
        for (int l = 0; l < 3; l++)
            cov[i][l] = M[i][0] * Rc[l][0] + M[i][1] * Rc[l][1] + M[i][2] * Rc[l][2];

    // ---- ray direction: d = normalize(Kinv @ [u,v,1]); dirs = Rc @ d ----
    const float u = coords[pix * 2 + 0];
    const float v = coords[pix * 2 + 1];
    float d0 = (u - cx) / fx;
    float d1 = (v - cy) / fy;
    float d2 = 1.0f;
    {
        const float nrm = sqrtf(d0 * d0 + d1 * d1 + d2 * d2);
        d0 /= nrm; d1 /= nrm; d2 /= nrm;
    }
    float dirs[3];
    #pragma unroll
    for (int i = 0; i < 3; i++)
        dirs[i] = Rc[i][0] * d0 + Rc[i][1] * d1 + Rc[i][2] * d2;

    const float dep = depths[pix];
    float means[3];
    #pragma unroll
    for (int i = 0; i < 3; i++) means[i] = tvec[i] + dirs[i] * dep;

    // ---- harmonics: D1[i][j] = Rc[perm[i]][perm[j]], perm=[1,2,0] ----
    const int perm[3] = {1, 2, 0};
    float harm[3][4];
    #pragma unroll
    for (int c = 0; c < 3; c++) {
        harm[c][0] = sh[c][0];
        #pragma unroll
        for (int i = 0; i < 3; i++) {
            float acc = 0.0f;
            #pragma unroll
            for (int j = 0; j < 3; j++)
                acc += Rc[perm[i]][perm[j]] * sh[c][1 + j];
            harm[c][1 + i] = acc;
        }
    }

    // ---- writes ----
    {
        float* o = out + OFF_MEANS + pix * 3;
        #pragma unroll
        for (int i = 0; i < 3; i++) o[i] = means[i];
    }
    {
        float* o = out + OFF_COV + pix * 9;
        #pragma unroll
        for (int i = 0; i < 3; i++)
            #pragma unroll
            for (int j = 0; j < 3; j++) o[i * 3 + j] = cov[i][j];
    }
    {
        float* o = out + OFF_SCALES + pix * 3;
        #pragma unroll
        for (int i = 0; i < 3; i++) o[i] = sc[i];
    }
    {
        float* o = out + OFF_ROT + pix * 4;
        #pragma unroll
        for (int i = 0; i < 4; i++) o[i] = q[i];
    }
    {
        float* o = out + OFF_HARM + pix * 12;
        #pragma unroll
        for (int c = 0; c < 3; c++)
            #pragma unroll
            for (int j = 0; j < 4; j++) o[c * 4 + j] = harm[c][j];
    }
    out[OFF_OPAC + pix] = opac[pix];   // exact pass-through
}

extern "C" void kernel_launch(void* const* d_in, const int* in_sizes, int n_in,
                              void* d_out, int out_size, void* d_ws, size_t ws_size,
                              hipStream_t stream) {
    const float* extr   = (const float*)d_in[0];
    const float* intr   = (const float*)d_in[1];
    const float* coords = (const float*)d_in[2];
    const float* depths = (const float*)d_in[3];
    const float* opac   = (const float*)d_in[4];
    const float* raw    = (const float*)d_in[5];
    const float* imgs   = (const float*)d_in[6];
    const float* shmask = (const float*)d_in[7];
    float* out = (float*)d_out;

    dim3 grid(R_PIX / 256, NVIEW);   // 484 x 8, exact cover
    dim3 block(256);
    gaussian_adapter_kernel<<<grid, block, 0, stream>>>(
        extr, intr, coords, depths, opac, raw, imgs, shmask, out);
}

// Round 3
// 226.000 us; speedup vs baseline: 1.0032x; 1.0032x over previous
//
#include <hip/hip_runtime.h>

// Problem constants
#define R_PIX 123904            // 352*352
#define NVIEW 8                 // B*V
#define NPIX  (R_PIX * (size_t)NVIEW)   // 991232

// Output element offsets (flat, fp32 elements)
#define OFF_MEANS  ((size_t)0)
#define OFF_COV    ((size_t)(3  * NPIX))
#define OFF_SCALES ((size_t)(12 * NPIX))
#define OFF_ROT    ((size_t)(15 * NPIX))
#define OFF_HARM   ((size_t)(19 * NPIX))
#define OFF_OPAC   ((size_t)(31 * NPIX))

// LDS layout (dwords). Input staging (4864 dw) reuses the same buffer.
#define MEANS_L  0       // 256*3  = 768
#define COV_L    768     // 256*9  = 2304
#define SCALES_L 3072    // 256*3  = 768
#define HARM_L   3840    // 256*13 = 3328 (stride 13: 12 payload + 1 pad, odd => bank-free)
#define LDS_DW   7168    // 28 KiB -> 5 blocks/CU

__global__ __launch_bounds__(256) void gaussian_adapter_kernel(
    const float* __restrict__ extr,    // [8,16]
    const float* __restrict__ intr,    // [8,9]
    const float* __restrict__ coords,  // [8, R, 2]
    const float* __restrict__ depths,  // [8, R]
    const float* __restrict__ opac,    // [8, R]
    const float* __restrict__ raw,     // [8, R, 19]
    const float* __restrict__ imgs,    // [8, 3, R]
    const float* __restrict__ shmask,  // [4]
    float* __restrict__ out)
{
    const int t   = threadIdx.x;
    const int bv  = blockIdx.y;
    const int bp0 = blockIdx.x * 256;                 // pixel-in-view base
    const size_t base_pix = (size_t)bv * R_PIX + bp0; // global pixel base (contiguous 256)
    const int p   = bp0 + t;
    const size_t pix = base_pix + t;

    __shared__ __align__(16) float lds[LDS_DW];

    // ---- stage raw block (256*19 = 4864 dw = 1216 vec4) coalesced ----
    {
        const float4* g = (const float4*)(raw + base_pix * 19);
        float4* s = (float4*)lds;
        #pragma unroll
        for (int i = 0; i < 4; i++) s[t + 256 * i] = g[t + 256 * i];
        if (t < 192) s[t + 1024] = g[t + 1024];
    }

    // ---- per-view constants (broadcast, L1) ----
    float Rc[3][3], tvec[3];
    {
        const float* E = extr + bv * 16;
        #pragma unroll
        for (int i = 0; i < 3; i++) {
            #pragma unroll
            for (int j = 0; j < 3; j++) Rc[i][j] = E[i * 4 + j];
            tvec[i] = E[i * 4 + 3];
        }
    }
    const float* K = intr + bv * 9;
    const float fx = K[0], cx = K[2];
    const float fy = K[4], cy = K[5];
    float sm[4];
    #pragma unroll
    for (int j = 0; j < 4; j++) sm[j] = shmask[j];

    __syncthreads();

    // ---- read this thread's 19 raw values (stride 19: odd => conflict-free) ----
    float rg[19];
    #pragma unroll
    for (int i = 0; i < 19; i++) rg[i] = lds[t * 19 + i];

    // ---- scales: clip(softplus(raw-4), 0.5, 15) ----
    float sc[3];
    #pragma unroll
    for (int k = 0; k < 3; k++) {
        float xv = rg[k] - 4.0f;
        float sp = fmaxf(xv, 0.0f) + log1pf(expf(-fabsf(xv)));
        sc[k] = fminf(fmaxf(sp, 0.5f), 15.0f);
    }

    // ---- rotations: q / (||q|| + 1e-8) ----
    float q[4];
    float qn = 0.0f;
    #pragma unroll
    for (int k = 0; k < 4; k++) { q[k] = rg[3 + k]; qn += q[k] * q[k]; }
    const float inorm = 1.0f / (sqrtf(qn) + 1e-8f);
    #pragma unroll
    for (int k = 0; k < 4; k++) q[k] *= inorm;

    // ---- sh = raw[7:].reshape(3,4) * sh_mask; DC += (img-0.5)/C0 ----
    float sh[3][4];
    #pragma unroll
    for (int c = 0; c < 3; c++)
        #pragma unroll
        for (int j = 0; j < 4; j++) sh[c][j] = rg[7 + c * 4 + j] * sm[j];
    {
        const float invC0 = 1.0f / 0.28209479177387814f;
        #pragma unroll
        for (int c = 0; c < 3; c++) {
            float im = imgs[((size_t)bv * 3 + c) * R_PIX + p];   // stride-1, coalesced
            sh[c][0] += (im - 0.5f) * invC0;
        }
    }

    // ---- quat -> rotation matrix ----
    const float qw = q[0], qx = q[1], qy = q[2], qz = q[3];
    const float two_s = 2.0f / (qw * qw + qx * qx + qy * qy + qz * qz);
    float Rq[3][3];
    Rq[0][0] = 1.0f - two_s * (qy * qy + qz * qz);
    Rq[0][1] = two_s * (qx * qy - qz * qw);
    Rq[0][2] = two_s * (qx * qz + qy * qw);
    Rq[1][0] = two_s * (qx * qy + qz * qw);
    Rq[1][1] = 1.0f - two_s * (qx * qx + qz * qz);
    Rq[1][2] = two_s * (qy * qz - qx * qw);
    Rq[2][0] = two_s * (qx * qz - qy * qw);
    Rq[2][1] = two_s * (qy * qz + qx * qw);
    Rq[2][2] = 1.0f - two_s * (qx * qx + qy * qy);

    // ---- cov = Rc (Rq diag(s^2) Rq^T) Rc^T ----
    const float s2[3] = { sc[0] * sc[0], sc[1] * sc[1], sc[2] * sc[2] };
    float cov3[3][3];
    #pragma unroll
    for (int i = 0; i < 3; i++)
        #pragma unroll
        for (int k = 0; k < 3; k++)
            cov3[i][k] = Rq[i][0] * s2[0] * Rq[k][0]
                       + Rq[i][1] * s2[1] * Rq[k][1]
                       + Rq[i][2] * s2[2] * Rq[k][2];
    float M[3][3];
    #pragma unroll
    for (int i = 0; i < 3; i++)
        #pragma unroll
        for (int k = 0; k < 3; k++)
            M[i][k] = Rc[i][0] * cov3[0][k] + Rc[i][1] * cov3[1][k] + Rc[i][2] * cov3[2][k];
    float cov[3][3];
    #pragma unroll
    for (int i = 0; i < 3; i++)
        #pragma unroll
        for (int l = 0; l < 3; l++)
            cov[i][l] = M[i][0] * Rc[l][0] + M[i][1] * Rc[l][1] + M[i][2] * Rc[l][2];

    // ---- means: t + Rc @ normalize(Kinv [u,v,1]) * depth ----
    float u, v;
    {
        const float2 uv = ((const float2*)coords)[pix];   // 8B coalesced
        u = uv.x; v = uv.y;
    }
    float d0 = (u - cx) / fx;
    float d1 = (v - cy) / fy;
    float d2 = 1.0f;
    {
        const float nrm = sqrtf(d0 * d0 + d1 * d1 + d2 * d2);
        d0 /= nrm; d1 /= nrm; d2 /= nrm;
    }
    const float dep = depths[pix];                        // stride-1, coalesced
    float means[3];
    #pragma unroll
    for (int i = 0; i < 3; i++)
        means[i] = tvec[i] + (Rc[i][0] * d0 + Rc[i][1] * d1 + Rc[i][2] * d2) * dep;

    // ---- harmonics: D1[i][j] = Rc[perm[i]][perm[j]], perm=[1,2,0] ----
    const int perm[3] = {1, 2, 0};
    float harm[3][4];
    #pragma unroll
    for (int c = 0; c < 3; c++) {
        harm[c][0] = sh[c][0];
        #pragma unroll
        for (int i = 0; i < 3; i++) {
            float acc = 0.0f;
            #pragma unroll
            for (int j = 0; j < 3; j++)
                acc += Rc[perm[i]][perm[j]] * sh[c][1 + j];
            harm[c][1 + i] = acc;
        }
    }

    // ---- direct coalesced stores (no transpose needed) ----
    ((float4*)(out + OFF_ROT))[pix] = make_float4(q[0], q[1], q[2], q[3]); // 16B/pixel
    out[OFF_OPAC + pix] = opac[pix];                                      // stride-1

    __syncthreads();   // all raw-staging reads done; safe to overwrite lds

    // ---- scatter outputs into LDS (all odd strides => conflict-free) ----
    #pragma unroll
    for (int i = 0; i < 3; i++) lds[MEANS_L + t * 3 + i] = means[i];
    #pragma unroll
    for (int i = 0; i < 3; i++)
        #pragma unroll
        for (int j = 0; j < 3; j++) lds[COV_L + t * 9 + i * 3 + j] = cov[i][j];
    #pragma unroll
    for (int i = 0; i < 3; i++) lds[SCALES_L + t * 3 + i] = sc[i];
    #pragma unroll
    for (int c = 0; c < 3; c++)
        #pragma unroll
        for (int j = 0; j < 4; j++) lds[HARM_L + t * 13 + c * 4 + j] = harm[c][j];

    __syncthreads();

    // ---- coalesced vec4 global stores ----
    {   // means: 768 dw = 192 vec4
        float4* g = (float4*)(out + OFF_MEANS + base_pix * 3);
        const float4* s = (const float4*)(lds + MEANS_L);
        if (t < 192) g[t] = s[t];
    }
    {   // cov: 2304 dw = 576 vec4
        float4* g = (float4*)(out + OFF_COV + base_pix * 9);
        const float4* s = (const float4*)(lds + COV_L);
        g[t] = s[t];
        g[t + 256] = s[t + 256];
        if (t < 64) g[t + 512] = s[t + 512];
    }
    {   // scales: 192 vec4
        float4* g = (float4*)(out + OFF_SCALES + base_pix * 3);
        const float4* s = (const float4*)(lds + SCALES_L);
        if (t < 192) g[t] = s[t];
    }
    {   // harm: 3072 dw = 768 vec4 (LDS padded to 13/pixel; 4 | 12 so each
        //       vec4 is within one pixel => contiguous 4 dwords in LDS)
        float4* g = (float4*)(out + OFF_HARM + base_pix * 12);
        #pragma unroll
        for (int it = 0; it < 3; it++) {
            int i = t + 256 * it;                 // vec4 index, 0..767
            int px = i / 3, k = i % 3;
            const float* s = lds + HARM_L + px * 13 + k * 4;
            g[i] = make_float4(s[0], s[1], s[2], s[3]);
        }
    }
}

extern "C" void kernel_launch(void* const* d_in, const int* in_sizes, int n_in,
                              void* d_out, int out_size, void* d_ws, size_t ws_size,
                              hipStream_t stream) {
    const float* extr   = (const float*)d_in[0];
    const float* intr   = (const float*)d_in[1];
    const float* coords = (const float*)d_in[2];
    const float* depths = (const float*)d_in[3];
    const float* opac   = (const float*)d_in[4];
    const float* raw    = (const float*)d_in[5];
    const float* imgs   = (const float*)d_in[6];
    const float* shmask = (const float*)d_in[7];
    float* out = (float*)d_out;

    dim3 grid(R_PIX / 256, NVIEW);   // 484 x 8, exact cover
    dim3 block(256);
    gaussian_adapter_kernel<<<grid, block, 0, stream>>>(
        extr, intr, coords, depths, opac, raw, imgs, shmask, out);
}

// Round 4
// 221.964 us; speedup vs baseline: 1.0214x; 1.0182x over previous
//
#include <hip/hip_runtime.h>

// Problem constants
#define R_PIX 123904            // 352*352
#define NVIEW 8                 // B*V
#define NPIX  (R_PIX * (size_t)NVIEW)   // 991232

// Output element offsets (flat, fp32 elements)
#define OFF_MEANS  ((size_t)0)
#define OFF_COV    ((size_t)(3  * NPIX))
#define OFF_SCALES ((size_t)(12 * NPIX))
#define OFF_ROT    ((size_t)(15 * NPIX))
#define OFF_HARM   ((size_t)(19 * NPIX))
#define OFF_OPAC   ((size_t)(31 * NPIX))

// LDS: 4864 dw = 19 KiB = exactly the raw staging size (256*19).
// Reused in two output phases:
//   phase A: means(768) + cov(2304) + scales(768) = 3840 dw
//   phase B: harm 256*13 = 3328 dw (stride 13 = 12 payload + 1 pad, odd)
// 19 KiB/block -> 8 blocks/CU -> 2048 threads = 100% occupancy (was 28 KiB -> 5 blocks -> 62.5%)
#define LDS_DW   4864
#define MEANS_L  0
#define COV_L    768
#define SCALES_L 3072
#define HARM_L   0

__global__ __launch_bounds__(256) void gaussian_adapter_kernel(
    const float* __restrict__ extr,    // [8,16]
    const float* __restrict__ intr,    // [8,9]
    const float* __restrict__ coords,  // [8, R, 2]
    const float* __restrict__ depths,  // [8, R]
    const float* __restrict__ opac,    // [8, R]
    const float* __restrict__ raw,     // [8, R, 19]
    const float* __restrict__ imgs,    // [8, 3, R]
    const float* __restrict__ shmask,  // [4]
    float* __restrict__ out)
{
    const int t   = threadIdx.x;
    const int bv  = blockIdx.y;
    const int bp0 = blockIdx.x * 256;
    const size_t base_pix = (size_t)bv * R_PIX + bp0;
    const int p   = bp0 + t;
    const size_t pix = base_pix + t;

    __shared__ __align__(16) float lds[LDS_DW];

    // ---- stage raw block (256*19 = 4864 dw = 1216 vec4) coalesced ----
    {
        const float4* g = (const float4*)(raw + base_pix * 19);
        float4* s = (float4*)lds;
        #pragma unroll
        for (int i = 0; i < 4; i++) s[t + 256 * i] = g[t + 256 * i];
        if (t < 192) s[t + 1024] = g[t + 1024];
    }

    // ---- per-view constants (broadcast, L1) ----
    float Rc[3][3], tvec[3];
    {
        const float* E = extr + bv * 16;
        #pragma unroll
        for (int i = 0; i < 3; i++) {
            #pragma unroll
            for (int j = 0; j < 3; j++) Rc[i][j] = E[i * 4 + j];
            tvec[i] = E[i * 4 + 3];
        }
    }
    const float* K = intr + bv * 9;
    const float fx = K[0], cx = K[2];
    const float fy = K[4], cy = K[5];
    float sm[4];
    #pragma unroll
    for (int j = 0; j < 4; j++) sm[j] = shmask[j];

    __syncthreads();

    // ---- read this thread's 19 raw values (stride 19: odd => conflict-free) ----
    float rg[19];
    #pragma unroll
    for (int i = 0; i < 19; i++) rg[i] = lds[t * 19 + i];

    __syncthreads();   // staging buffer free for reuse after this

    // ---- scales: clip(softplus(raw-4), 0.5, 15) ----
    float sc[3];
    #pragma unroll
    for (int k = 0; k < 3; k++) {
        float xv = rg[k] - 4.0f;
        float sp = fmaxf(xv, 0.0f) + log1pf(expf(-fabsf(xv)));
        sc[k] = fminf(fmaxf(sp, 0.5f), 15.0f);
    }

    // ---- rotations: q / (||q|| + 1e-8) ----
    float q[4];
    float qn = 0.0f;
    #pragma unroll
    for (int k = 0; k < 4; k++) { q[k] = rg[3 + k]; qn += q[k] * q[k]; }
    const float inorm = 1.0f / (sqrtf(qn) + 1e-8f);
    #pragma unroll
    for (int k = 0; k < 4; k++) q[k] *= inorm;

    // ---- sh = raw[7:].reshape(3,4) * sh_mask; DC += (img-0.5)/C0 ----
    float sh[3][4];
    #pragma unroll
    for (int c = 0; c < 3; c++)
        #pragma unroll
        for (int j = 0; j < 4; j++) sh[c][j] = rg[7 + c * 4 + j] * sm[j];
    {
        const float invC0 = 1.0f / 0.28209479177387814f;
        #pragma unroll
        for (int c = 0; c < 3; c++) {
            float im = imgs[((size_t)bv * 3 + c) * R_PIX + p];   // stride-1, coalesced
            sh[c][0] += (im - 0.5f) * invC0;
        }
    }

    // ---- quat -> rotation matrix ----
    const float qw = q[0], qx = q[1], qy = q[2], qz = q[3];
    const float two_s = 2.0f / (qw * qw + qx * qx + qy * qy + qz * qz);
    float Rq[3][3];
    Rq[0][0] = 1.0f - two_s * (qy * qy + qz * qz);
    Rq[0][1] = two_s * (qx * qy - qz * qw);
    Rq[0][2] = two_s * (qx * qz + qy * qw);
    Rq[1][0] = two_s * (qx * qy + qz * qw);
    Rq[1][1] = 1.0f - two_s * (qx * qx + qz * qz);
    Rq[1][2] = two_s * (qy * qz - qx * qw);
    Rq[2][0] = two_s * (qx * qz - qy * qw);
    Rq[2][1] = two_s * (qy * qz + qx * qw);
    Rq[2][2] = 1.0f - two_s * (qx * qx + qy * qy);

    // ---- cov = Rc (Rq diag(s^2) Rq^T) Rc^T ----
    const float s2[3] = { sc[0] * sc[0], sc[1] * sc[1], sc[2] * sc[2] };
    float cov3[3][3];
    #pragma unroll
    for (int i = 0; i < 3; i++)
        #pragma unroll
        for (int k = 0; k < 3; k++)
            cov3[i][k] = Rq[i][0] * s2[0] * Rq[k][0]
                       + Rq[i][1] * s2[1] * Rq[k][1]
                       + Rq[i][2] * s2[2] * Rq[k][2];
    float M[3][3];
    #pragma unroll
    for (int i = 0; i < 3; i++)
        #pragma unroll
        for (int k = 0; k < 3; k++)
            M[i][k] = Rc[i][0] * cov3[0][k] + Rc[i][1] * cov3[1][k] + Rc[i][2] * cov3[2][k];
    float cov[3][3];
    #pragma unroll
    for (int i = 0; i < 3; i++)
        #pragma unroll
        for (int l = 0; l < 3; l++)
            cov[i][l] = M[i][0] * Rc[l][0] + M[i][1] * Rc[l][1] + M[i][2] * Rc[l][2];

    // ---- means: t + Rc @ normalize(Kinv [u,v,1]) * depth ----
    float u, v;
    {
        const float2 uv = ((const float2*)coords)[pix];   // 8B coalesced
        u = uv.x; v = uv.y;
    }
    float d0 = (u - cx) / fx;
    float d1 = (v - cy) / fy;
    float d2 = 1.0f;
    {
        const float rn = 1.0f / sqrtf(d0 * d0 + d1 * d1 + d2 * d2);
        d0 *= rn; d1 *= rn; d2 *= rn;
    }
    const float dep = depths[pix];                        // stride-1, coalesced
    float means[3];
    #pragma unroll
    for (int i = 0; i < 3; i++)
        means[i] = tvec[i] + (Rc[i][0] * d0 + Rc[i][1] * d1 + Rc[i][2] * d2) * dep;

    // ---- harmonics: D1[i][j] = Rc[perm[i]][perm[j]], perm=[1,2,0] ----
    const int perm[3] = {1, 2, 0};
    float harm[3][4];
    #pragma unroll
    for (int c = 0; c < 3; c++) {
        harm[c][0] = sh[c][0];
        #pragma unroll
        for (int i = 0; i < 3; i++) {
            float acc = 0.0f;
            #pragma unroll
            for (int j = 0; j < 3; j++)
                acc += Rc[perm[i]][perm[j]] * sh[c][1 + j];
            harm[c][1 + i] = acc;
        }
    }

    // ---- direct coalesced stores (already aligned/dense) ----
    ((float4*)(out + OFF_ROT))[pix] = make_float4(q[0], q[1], q[2], q[3]); // 16B/pixel
    out[OFF_OPAC + pix] = opac[pix];                                      // stride-1

    // ======== phase A: means + cov + scales through LDS (3840 dw) ========
    #pragma unroll
    for (int i = 0; i < 3; i++) lds[MEANS_L + t * 3 + i] = means[i];
    #pragma unroll
    for (int i = 0; i < 3; i++)
        #pragma unroll
        for (int j = 0; j < 3; j++) lds[COV_L + t * 9 + i * 3 + j] = cov[i][j];
    #pragma unroll
    for (int i = 0; i < 3; i++) lds[SCALES_L + t * 3 + i] = sc[i];

    __syncthreads();

    {   // means: 768 dw = 192 vec4
        float4* g = (float4*)(out + OFF_MEANS + base_pix * 3);
        const float4* s = (const float4*)(lds + MEANS_L);
        if (t < 192) g[t] = s[t];
    }
    {   // cov: 2304 dw = 576 vec4
        float4* g = (float4*)(out + OFF_COV + base_pix * 9);
        const float4* s = (const float4*)(lds + COV_L);
        g[t] = s[t];
        g[t + 256] = s[t + 256];
        if (t < 64) g[t + 512] = s[t + 512];
    }
    {   // scales: 192 vec4
        float4* g = (float4*)(out + OFF_SCALES + base_pix * 3);
        const float4* s = (const float4*)(lds + SCALES_L);
        if (t < 192) g[t] = s[t];
    }

    __syncthreads();

    // ======== phase B: harm through LDS (256*13 = 3328 dw, stride 13) ========
    #pragma unroll
    for (int c = 0; c < 3; c++)
        #pragma unroll
        for (int j = 0; j < 4; j++) lds[HARM_L + t * 13 + c * 4 + j] = harm[c][j];

    __syncthreads();

    {   // harm: 3072 dw = 768 vec4; 4 | 12 so each vec4 lies within one pixel's pad-13 row
        float4* g = (float4*)(out + OFF_HARM + base_pix * 12);
        #pragma unroll
        for (int it = 0; it < 3; it++) {
            int i = t + 256 * it;                 // vec4 index, 0..767
            int px = i / 3, k = i % 3;
            const float* s = lds + HARM_L + px * 13 + k * 4;
            g[i] = make_float4(s[0], s[1], s[2], s[3]);
        }
    }
}

extern "C" void kernel_launch(void* const* d_in, const int* in_sizes, int n_in,
                              void* d_out, int out_size, void* d_ws, size_t ws_size,
                              hipStream_t stream) {
    const float* extr   = (const float*)d_in[0];
    const float* intr   = (const float*)d_in[1];
    const float* coords = (const float*)d_in[2];
    const float* depths = (const float*)d_in[3];
    const float* opac   = (const float*)d_in[4];
    const float* raw    = (const float*)d_in[5];
    const float* imgs   = (const float*)d_in[6];
    const float* shmask = (const float*)d_in[7];
    float* out = (float*)d_out;

    dim3 grid(R_PIX / 256, NVIEW);   // 484 x 8, exact cover
    dim3 block(256);
    gaussian_adapter_kernel<<<grid, block, 0, stream>>>(
        extr, intr, coords, depths, opac, raw, imgs, shmask, out);
}